// Round 1
// baseline (227.169 us; speedup 1.0000x reference)
//
#include <hip/hip_runtime.h>

#define TAU 0.2f
#define VTH 0.3f

// x: [B, C, H, W, T] fp32, T=8 innermost and contiguous.
// One thread per (B,C,H,W) pixel: load 8 contiguous floats as 2x float4,
// run the LIF scan in registers, store 8 spikes as 2x float4.
__global__ __launch_bounds__(256) void LIFSpike_73864847556979_kernel(
    const float* __restrict__ x, float* __restrict__ out, int n_pixels) {
    int idx = blockIdx.x * blockDim.x + threadIdx.x;
    if (idx >= n_pixels) return;

    const float4* __restrict__ xp = (const float4*)(x + (size_t)idx * 8);
    float4 a = xp[0];
    float4 b = xp[1];

    float v[8] = {a.x, a.y, a.z, a.w, b.x, b.y, b.z, b.w};
    float r[8];

    float u = 0.0f;
    float o = 0.0f;
#pragma unroll
    for (int t = 0; t < 8; ++t) {
        u = TAU * u * (1.0f - o) + v[t];
        o = (u - VTH > 0.0f) ? 1.0f : 0.0f;
        r[t] = o;
    }

    float4* __restrict__ op = (float4*)(out + (size_t)idx * 8);
    op[0] = make_float4(r[0], r[1], r[2], r[3]);
    op[1] = make_float4(r[4], r[5], r[6], r[7]);
}

extern "C" void kernel_launch(void* const* d_in, const int* in_sizes, int n_in,
                              void* d_out, int out_size, void* d_ws, size_t ws_size,
                              hipStream_t stream) {
    const float* x = (const float*)d_in[0];
    float* out = (float*)d_out;
    int n_pixels = in_sizes[0] / 8;  // T = 8
    int block = 256;
    int grid = (n_pixels + block - 1) / block;
    LIFSpike_73864847556979_kernel<<<grid, block, 0, stream>>>(x, out, n_pixels);
}